// Round 3
// baseline (357.651 us; speedup 1.0000x reference)
//
#include <hip/hip_runtime.h>

// Problem: single-head causal attention.
// B=512, T=256, C=384, H=64. Inputs fp32: x[B,T,C], Wq/Wk/Wv[C,H]. Out fp32 [B,T,H].
// Scale is C^-0.5 (note: n_embed, not head_size).
#define B_ 512
#define T_ 256
#define C_ 384
#define H_ 64

typedef __attribute__((ext_vector_type(8))) short bf16x8;   // 4 VGPRs, MFMA A/B frag
typedef __attribute__((ext_vector_type(4))) float f32x4;    // MFMA C/D frag

// fp32 -> bf16 (RNE). Data is finite; no NaN handling needed.
__device__ __forceinline__ short f2bf(float f) {
    unsigned u = __float_as_uint(f);
    u += 0x7fffu + ((u >> 16) & 1u);
    return (short)(u >> 16);
}

// Load 8 consecutive fp32 and convert to a bf16x8 A-fragment (two dwordx4 loads).
__device__ __forceinline__ bf16x8 cvt8(const float* p) {
    const float4* p4 = (const float4*)p;
    float4 a = p4[0], b = p4[1];
    bf16x8 r;
    r[0] = f2bf(a.x); r[1] = f2bf(a.y); r[2] = f2bf(a.z); r[3] = f2bf(a.w);
    r[4] = f2bf(b.x); r[5] = f2bf(b.y); r[6] = f2bf(b.z); r[7] = f2bf(b.w);
    return r;
}

// ---------------------------------------------------------------------------
// Kernel 0: pack Wq|Wk|Wv (fp32, [C][H] each) into bf16 MFMA B-fragment order.
// Combined N = 192 (q:0-63, k:64-127, v:128-191). K = C = 384.
// Packed index p = ((ks*12 + ct)*64 + lane)*8 + j,
//   where n = ct*16 + (lane&15), k = ks*32 + (lane>>4)*8 + j.
// ---------------------------------------------------------------------------
__global__ void pack_w_kernel(const float* __restrict__ Wq, const float* __restrict__ Wk,
                              const float* __restrict__ Wv, short* __restrict__ wp) {
    int p = blockIdx.x * 256 + threadIdx.x;
    if (p >= 12 * 12 * 512) return;           // 73728 shorts total
    int j    = p & 7;
    int lane = (p >> 3) & 63;
    int pc   = p >> 9;                         // ks*12 + ct
    int ct = pc % 12, ks = pc / 12;
    int n  = ct * 16 + (lane & 15);
    int kk = ks * 32 + (lane >> 4) * 8 + j;
    const float* src = (n < 64) ? Wq : ((n < 128) ? Wk : Wv);
    wp[p] = f2bf(src[kk * 64 + (n & 63)]);
}

// ---------------------------------------------------------------------------
// Kernel 1: QKV projection GEMM. M = B*T = 131072, K = 384, N = 192.
// R2 rewrite: NO LDS, NO barriers. W (144 KB) is L2-resident and the per-ks
// working set (12 KB) is L1-resident, so B-frags are read directly from
// global (coalesced 1 KB/instr). Every iteration is independent -> the
// compiler can pipeline loads across the whole K loop (fine-grained vmcnt),
// no syncthreads vmcnt(0) drain. x A-frags read from global exactly once
// (16 rows x 128 B per wave-instruction, fully coalesced).
// ---------------------------------------------------------------------------
__global__ __launch_bounds__(256, 2) void qkv_kernel(
    const float* __restrict__ x, const short* __restrict__ wp,
    short* __restrict__ qo, short* __restrict__ ko, short* __restrict__ vo) {
    const int tid  = threadIdx.x;
    const int lane = tid & 63, w = tid >> 6;
    const int cl = lane & 15, quad = lane >> 4;
    const int rowbase = blockIdx.x * 128;

    const float* xr0 = x + (long)(rowbase + w * 32 + cl) * C_;  // row-tile 0 (m = cl)
    const float* xr1 = xr0 + 16 * C_;                           // row-tile 1

    f32x4 acc[2][12];
    #pragma unroll
    for (int rt = 0; rt < 2; rt++)
        #pragma unroll
        for (int ct = 0; ct < 12; ct++) {
            f32x4 z = {0.f, 0.f, 0.f, 0.f};
            acc[rt][ct] = z;
        }

    const short* wl = wp + lane * 8;          // lane's slot within each frag
    for (int ks = 0; ks < 12; ks++) {
        const int koff = ks * 32 + quad * 8;  // A-frag k = quad*8 + j
        bf16x8 a0 = cvt8(xr0 + koff);
        bf16x8 a1 = cvt8(xr1 + koff);
        const short* wk = wl + ks * 6144;     // ks-chunk = 12 frags x 512 shorts
        #pragma unroll
        for (int ct = 0; ct < 12; ct++) {
            bf16x8 bf = *(const bf16x8*)(wk + ct * 512);
            acc[0][ct] = __builtin_amdgcn_mfma_f32_16x16x32_bf16(a0, bf, acc[0][ct], 0, 0, 0);
            acc[1][ct] = __builtin_amdgcn_mfma_f32_16x16x32_bf16(a1, bf, acc[1][ct], 0, 0, 0);
        }
    }

    // Epilogue. C/D layout: col n = ct*16 + (lane&15), row = quad*4 + reg.
    #pragma unroll
    for (int rt = 0; rt < 2; rt++) {
        const int gb = rowbase + w * 32 + rt * 16 + quad * 4;
        #pragma unroll
        for (int ct = 0; ct < 12; ct++) {
            const int n = ct * 16 + cl;
            short* dstp = (n < 64) ? qo : ((n < 128) ? ko : vo);
            const int nn = n & 63;
            #pragma unroll
            for (int r = 0; r < 4; r++)
                dstp[(long)(gb + r) * 64 + nn] = f2bf(acc[rt][ct][r]);
        }
    }
}

// ---------------------------------------------------------------------------
// Kernel 2: causal attention. R2: TWO blocks (256 thr = 4 waves) per batch
// instead of one 512-thr block: __launch_bounds__(256,3) -> 170-VGPR budget
// (old (512,4) capped at 128 -> spill risk with sacc[16]=64 VGPRs live),
// and 3-4 independent blocks/CU for latency hiding.
// Block-half p owns row-groups {4p+w, 15-(4p+w)} per wave -> 68 S-tiles per
// half (balanced). V[b] staged transposed in LDS (Vs[h][t], stride 264);
// staging reads are h-contiguous (coalesced 128 B) and writes are
// ds_write_b64 (minor conflicts only). K/Q frags from global (L1-resident:
// K[b] = 32 KB). Full-row softmax in registers, stats via __shfl_xor within
// each 16-lane quad. P: C-layout -> bf16 -> per-wave LDS chunk -> A-layout.
// ---------------------------------------------------------------------------
__global__ __launch_bounds__(256, 3) void attn_kernel(
    const short* __restrict__ qi, const short* __restrict__ ki,
    const short* __restrict__ vi, float* __restrict__ out) {
    __shared__ short Vs[64 * 264];            // 33792 B
    __shared__ short Pb[4][16 * 40];          // 5120 B

    const int b = blockIdx.x >> 1;
    const int ph = blockIdx.x & 1;            // which half of the row-groups
    const int tid = threadIdx.x;
    const int w = tid >> 6, lane = tid & 63;
    const int cl = lane & 15, quad = lane >> 4;

    // Stage V[b] (256x64 bf16, [t][h]) transposed into Vs[h][t].
    // Thread i handles (h = i&63, t-group tg = i>>6): 4 coalesced b16 global
    // reads (lanes sweep h for fixed t) + one ds_write_b64.
    const short* vb = vi + b * (T_ * H_);
    for (int i = tid; i < (T_ * H_ / 4); i += 256) {
        const int h = i & 63, tg = i >> 6;
        short4 val;
        val.x = vb[(tg * 4 + 0) * 64 + h];
        val.y = vb[(tg * 4 + 1) * 64 + h];
        val.z = vb[(tg * 4 + 2) * 64 + h];
        val.w = vb[(tg * 4 + 3) * 64 + h];
        *(short4*)(Vs + h * 264 + tg * 4) = val;
    }
    __syncthreads();

    const float scale = 0.05103103630798287f;  // 384^-0.5

    for (int it = 0; it < 2; it++) {
        const int rg0 = ph * 4 + w;
        const int rg = it ? (15 - rg0) : rg0;  // row-group: rows [16rg, 16rg+16)
        const int base = rg << 4;

        // Q A-frags for this row-group: m = cl, k(h) = 32*kk + quad*8 + j.
        const short* qb = qi + (long)(b * T_ + base + cl) * H_;
        const bf16x8 qf0 = *(const bf16x8*)(qb + quad * 8);
        const bf16x8 qf1 = *(const bf16x8*)(qb + 32 + quad * 8);

        // S = Q K^T, only tiles st <= rg (causal). Guards are wave-uniform.
        f32x4 sacc[16];
        #pragma unroll
        for (int st = 0; st < 16; st++) {
            if (st > rg) continue;
            const short* kb = ki + (long)(b * T_ + st * 16 + cl) * H_;  // n = s
            bf16x8 k0 = *(const bf16x8*)(kb + quad * 8);
            bf16x8 k1 = *(const bf16x8*)(kb + 32 + quad * 8);
            f32x4 z = {0.f, 0.f, 0.f, 0.f};
            f32x4 t = __builtin_amdgcn_mfma_f32_16x16x32_bf16(qf0, k0, z, 0, 0, 0);
            t = __builtin_amdgcn_mfma_f32_16x16x32_bf16(qf1, k1, t, 0, 0, 0);
            sacc[st] = t;
        }

        // Scale, causal mask (only diagonal tile st==rg can mask), row max.
        float m4[4] = {-3e38f, -3e38f, -3e38f, -3e38f};
        #pragma unroll
        for (int st = 0; st < 16; st++) {
            if (st > rg) continue;
            #pragma unroll
            for (int r = 0; r < 4; r++) {
                float sv = sacc[st][r] * scale;
                if (st * 16 + cl > base + quad * 4 + r) sv = -1e30f;
                sacc[st][r] = sv;
                m4[r] = fmaxf(m4[r], sv);
            }
        }
        #pragma unroll
        for (int d = 1; d < 16; d <<= 1)
            #pragma unroll
            for (int r = 0; r < 4; r++)
                m4[r] = fmaxf(m4[r], __shfl_xor(m4[r], d));

        // exp + row sum. Masked entries -> exp2(-huge) = 0 exactly.
        float l4[4] = {0.f, 0.f, 0.f, 0.f};
        #pragma unroll
        for (int st = 0; st < 16; st++) {
            if (st > rg) continue;
            #pragma unroll
            for (int r = 0; r < 4; r++) {
                float pv = exp2f((sacc[st][r] - m4[r]) * 1.4426950408889634f);
                sacc[st][r] = pv;
                l4[r] += pv;
            }
        }
        #pragma unroll
        for (int d = 1; d < 16; d <<= 1)
            #pragma unroll
            for (int r = 0; r < 4; r++)
                l4[r] += __shfl_xor(l4[r], d);

        // O = P V over s-chunks of 32 (chunks c <= rg/2). P round-trips LDS to
        // convert C/D layout -> A layout. Same-wave DS ops execute in order.
        f32x4 oacc[4];
        #pragma unroll
        for (int ht = 0; ht < 4; ht++) {
            f32x4 z = {0.f, 0.f, 0.f, 0.f};
            oacc[ht] = z;
        }
        short* pb = Pb[w];
        #pragma unroll
        for (int c = 0; c < 8; c++) {
            if (c > (rg >> 1)) continue;
            #pragma unroll
            for (int half = 0; half < 2; half++) {
                const int st = c * 2 + half;
                #pragma unroll
                for (int r = 0; r < 4; r++) {
                    short pv = (st <= rg) ? f2bf(sacc[st][r]) : (short)0;
                    pb[(quad * 4 + r) * 40 + half * 16 + cl] = pv;
                }
            }
            __builtin_amdgcn_wave_barrier();
            const bf16x8 pa = *(const bf16x8*)(pb + cl * 40 + quad * 8);  // m=cl, k=quad*8+j
            #pragma unroll
            for (int ht = 0; ht < 4; ht++) {
                const bf16x8 vf = *(const bf16x8*)(Vs + (ht * 16 + cl) * 264 + c * 32 + quad * 8);
                oacc[ht] = __builtin_amdgcn_mfma_f32_16x16x32_bf16(pa, vf, oacc[ht], 0, 0, 0);
            }
            __builtin_amdgcn_wave_barrier();  // keep next chunk's writes after this read
        }

        // Epilogue: O row r lives in the same lanes as l4[r] -> divide and store.
        #pragma unroll
        for (int r = 0; r < 4; r++) {
            const float inv = 1.0f / l4[r];
            float* op = out + (long)(b * T_ + base + quad * 4 + r) * H_ + cl;
            #pragma unroll
            for (int ht = 0; ht < 4; ht++)
                op[ht * 16] = oacc[ht][r] * inv;
        }
    }
}

// ---------------------------------------------------------------------------
extern "C" void kernel_launch(void* const* d_in, const int* in_sizes, int n_in,
                              void* d_out, int out_size, void* d_ws, size_t ws_size,
                              hipStream_t stream) {
    const float* x  = (const float*)d_in[0];
    const float* Wq = (const float*)d_in[1];
    const float* Wk = (const float*)d_in[2];
    const float* Wv = (const float*)d_in[3];
    float* out = (float*)d_out;

    // Workspace layout (bf16): q | k | v | packed W.  Total ~48.2 MiB.
    short* ws = (short*)d_ws;
    const long QKV = (long)B_ * T_ * H_;       // 8388608
    short* q  = ws;
    short* k  = ws + QKV;
    short* v  = ws + 2 * QKV;
    short* wp = ws + 3 * QKV;

    pack_w_kernel<<<288, 256, 0, stream>>>(Wq, Wk, Wv, wp);
    qkv_kernel<<<(B_ * T_) / 128, 256, 0, stream>>>(x, wp, q, k, v);
    attn_kernel<<<B_ * 2, 256, 0, stream>>>(q, k, v, out);
}

// Round 4
// 325.520 us; speedup vs baseline: 1.0987x; 1.0987x over previous
//
#include <hip/hip_runtime.h>

// Problem: single-head causal attention, FUSED (R3).
// B=512, T=256, C=384, H=64. Inputs fp32: x[B,T,C], Wq/Wk/Wv[C,H]. Out fp32 [B,T,H].
// Scale is C^-0.5 (note: n_embed, not head_size).
#define B_ 512
#define T_ 256
#define C_ 384
#define H_ 64

typedef __attribute__((ext_vector_type(8))) short bf16x8;   // 4 VGPRs, MFMA A/B frag
typedef __attribute__((ext_vector_type(4))) float f32x4;    // MFMA C/D frag

// fp32 -> bf16 (RNE). Data is finite; no NaN handling needed.
__device__ __forceinline__ short f2bf(float f) {
    unsigned u = __float_as_uint(f);
    u += 0x7fffu + ((u >> 16) & 1u);
    return (short)(u >> 16);
}

// Load 8 consecutive fp32 and convert to a bf16x8 A-fragment (two dwordx4 loads).
__device__ __forceinline__ bf16x8 cvt8(const float* p) {
    const float4* p4 = (const float4*)p;
    float4 a = p4[0], b = p4[1];
    bf16x8 r;
    r[0] = f2bf(a.x); r[1] = f2bf(a.y); r[2] = f2bf(a.z); r[3] = f2bf(a.w);
    r[4] = f2bf(b.x); r[5] = f2bf(b.y); r[6] = f2bf(b.z); r[7] = f2bf(b.w);
    return r;
}

// ---------------------------------------------------------------------------
// Kernel 0: pack Wq|Wk|Wv (fp32, [C][H] each) into bf16 MFMA B-fragment order.
// Combined N = 192 (q:0-63, k:64-127, v:128-191). K = C = 384.
// Packed index p = ((ks*12 + ct)*64 + lane)*8 + j,
//   where n = ct*16 + (lane&15), k = ks*32 + (lane>>4)*8 + j.
// ---------------------------------------------------------------------------
__global__ void pack_w_kernel(const float* __restrict__ Wq, const float* __restrict__ Wk,
                              const float* __restrict__ Wv, short* __restrict__ wp) {
    int p = blockIdx.x * 256 + threadIdx.x;
    if (p >= 12 * 12 * 512) return;           // 73728 shorts total
    int j    = p & 7;
    int lane = (p >> 3) & 63;
    int pc   = p >> 9;                         // ks*12 + ct
    int ct = pc % 12, ks = pc / 12;
    int n  = ct * 16 + (lane & 15);
    int kk = ks * 32 + (lane >> 4) * 8 + j;
    const float* src = (n < 64) ? Wq : ((n < 128) ? Wk : Wv);
    wp[p] = f2bf(src[kk * 64 + (n & 63)]);
}

// ---------------------------------------------------------------------------
// Kernel 1 (FUSED): one block of 512 thr (8 waves) per batch.
// Phase 1 (QKV): wave w computes q,k,v for rows [16w,16w+16) and
//   [240-16w,256-16w) — exactly its phase-2 row-groups {w, 15-w}. x A-frags
//   from global (coalesced, read once); W B-frags from packed wp (L2).
// Epilogue: K -> LDS Ks in QK-B-frag layout; V -> LDS Vs in PV-B-frag layout;
//   Q converted C->A layout in-wave via Pb round-trip, stays in registers.
// Phase 2 (attention): full-row softmax per 16-row group, S tiles st<=rg,
//   stats via __shfl_xor within 16-lane quads, P via Pb round-trip, PV from
//   Vs, out to global. q/k/v NEVER touch HBM (saves ~100 MB vs 3-kernel).
// LDS: Ks 32K + Vs 32K + Pb 10K = 75776 B -> 1 block/CU, 8 waves.
// ---------------------------------------------------------------------------
__global__ __launch_bounds__(512, 2) void fused_kernel(
    const float* __restrict__ x, const short* __restrict__ wp,
    float* __restrict__ out) {
    // Frag layout in Ks: frag(ts,kk) at (ts*2+kk)*512; element (t,h):
    //   lane' = (t&15) + 16*((h&31)>>3), j = h&7.  (t = key row, h = head dim)
    // Frag layout in Vs: frag(c,ht) at (c*4+ht)*512; element (t,h):
    //   lane' = (h&15) + 16*((t>>3)&3), j = t&7.   (k-dim = t, n-dim = h)
    __shared__ short Ks[32 * 512];            // 32768 B
    __shared__ short Vs[32 * 512];            // 32768 B
    __shared__ short Pb[8][16 * 40];          // 10240 B per-wave scratch

    const int b = blockIdx.x;
    const int tid = threadIdx.x;
    const int w = tid >> 6, lane = tid & 63;
    const int cl = lane & 15, quad = lane >> 4;

    // ---------------- Phase 1: QKV projection for this wave's 32 rows -------
    const float* xb = x + (long)b * (T_ * C_);
    const int r0 = 16 * w;                    // row-tile 0 base (rg = w)
    const int r1 = 240 - 16 * w;              // row-tile 1 base (rg = 15-w)
    const float* xr0 = xb + (long)(r0 + cl) * C_;
    const float* xr1 = xb + (long)(r1 + cl) * C_;

    f32x4 acc[2][12];
    #pragma unroll
    for (int rt = 0; rt < 2; rt++)
        #pragma unroll
        for (int ct = 0; ct < 12; ct++) {
            f32x4 z = {0.f, 0.f, 0.f, 0.f};
            acc[rt][ct] = z;
        }

    const short* wl = wp + lane * 8;
    for (int ks = 0; ks < 12; ks++) {
        const int koff = ks * 32 + quad * 8;  // A-frag k = quad*8 + j
        bf16x8 a0 = cvt8(xr0 + koff);
        bf16x8 a1 = cvt8(xr1 + koff);
        const short* wk = wl + ks * 6144;     // ks-chunk = 12 frags x 512 shorts
        #pragma unroll
        for (int ct = 0; ct < 12; ct++) {
            bf16x8 bf = *(const bf16x8*)(wk + ct * 512);
            acc[0][ct] = __builtin_amdgcn_mfma_f32_16x16x32_bf16(a0, bf, acc[0][ct], 0, 0, 0);
            acc[1][ct] = __builtin_amdgcn_mfma_f32_16x16x32_bf16(a1, bf, acc[1][ct], 0, 0, 0);
        }
    }

    // ---------------- Epilogue: K,V -> LDS; Q -> A-frags in registers -------
    // C/D layout: value acc[rt][ct][r] is element (t = rbase + quad*4 + r,
    // n = ct*16 + cl) where rbase = rt ? r1 : r0.
    #pragma unroll
    for (int rt = 0; rt < 2; rt++) {
        const int tb = (rt ? r1 : r0) + quad * 4;
        // K: ct 4..7, h = (ct-4)*16 + cl.
        #pragma unroll
        for (int ct = 4; ct < 8; ct++) {
            const int h = (ct - 4) * 16 + cl;
            const int kk = h >> 5, hq = (h & 31) >> 3, j = h & 7;
            #pragma unroll
            for (int r = 0; r < 4; r++) {
                const int t = tb + r;
                Ks[((t >> 4) * 2 + kk) * 512 + ((t & 15) + 16 * hq) * 8 + j] =
                    f2bf(acc[rt][ct][r]);
            }
        }
        // V: ct 8..11, h = (ct-8)*16 + cl, ht = ct-8.
        #pragma unroll
        for (int ct = 8; ct < 12; ct++) {
            const int ht = ct - 8;
            #pragma unroll
            for (int r = 0; r < 4; r++) {
                const int t = tb + r;
                Vs[((t >> 5) * 4 + ht) * 512 + (cl + 16 * ((t >> 3) & 3)) * 8 + (t & 7)] =
                    f2bf(acc[rt][ct][r]);
            }
        }
    }

    // Q: ct 0..3 (h = ct*16+cl). Convert C-layout -> A-frags via per-wave Pb.
    short* pb = Pb[w];
    bf16x8 qf[2][2];
    #pragma unroll
    for (int rt = 0; rt < 2; rt++)
        #pragma unroll
        for (int kk = 0; kk < 2; kk++) {
            #pragma unroll
            for (int cth = 0; cth < 2; cth++) {
                const int ct = kk * 2 + cth;
                #pragma unroll
                for (int r = 0; r < 4; r++)
                    pb[(quad * 4 + r) * 40 + cth * 16 + cl] = f2bf(acc[rt][ct][r]);
            }
            __builtin_amdgcn_wave_barrier();
            qf[rt][kk] = *(const bf16x8*)(pb + cl * 40 + quad * 8);  // m=cl, k=quad*8+j
            __builtin_amdgcn_wave_barrier();
        }

    __syncthreads();   // Ks/Vs written by all waves before any wave reads

    // ---------------- Phase 2: causal attention ----------------------------
    const float scale = 0.05103103630798287f;  // 384^-0.5

    #pragma unroll
    for (int it = 0; it < 2; it++) {
        const int rg = it ? (15 - w) : w;      // row-group: rows [16rg, 16rg+16)
        const int base = rg << 4;
        const bf16x8 qf0 = qf[it][0];
        const bf16x8 qf1 = qf[it][1];

        // S = Q K^T, tiles st <= rg (wave-uniform guards).
        f32x4 sacc[16];
        #pragma unroll
        for (int st = 0; st < 16; st++) {
            if (st > rg) continue;
            bf16x8 k0 = *(const bf16x8*)(Ks + (st * 2 + 0) * 512 + lane * 8);
            bf16x8 k1 = *(const bf16x8*)(Ks + (st * 2 + 1) * 512 + lane * 8);
            f32x4 z = {0.f, 0.f, 0.f, 0.f};
            f32x4 t = __builtin_amdgcn_mfma_f32_16x16x32_bf16(qf0, k0, z, 0, 0, 0);
            t = __builtin_amdgcn_mfma_f32_16x16x32_bf16(qf1, k1, t, 0, 0, 0);
            sacc[st] = t;
        }

        // Scale, causal mask (only diagonal tile st==rg masks), row max.
        float m4[4] = {-3e38f, -3e38f, -3e38f, -3e38f};
        #pragma unroll
        for (int st = 0; st < 16; st++) {
            if (st > rg) continue;
            #pragma unroll
            for (int r = 0; r < 4; r++) {
                float sv = sacc[st][r] * scale;
                if (st * 16 + cl > base + quad * 4 + r) sv = -1e30f;
                sacc[st][r] = sv;
                m4[r] = fmaxf(m4[r], sv);
            }
        }
        #pragma unroll
        for (int d = 1; d < 16; d <<= 1)
            #pragma unroll
            for (int r = 0; r < 4; r++)
                m4[r] = fmaxf(m4[r], __shfl_xor(m4[r], d));

        // exp + row sum (masked entries -> 0 exactly).
        float l4[4] = {0.f, 0.f, 0.f, 0.f};
        #pragma unroll
        for (int st = 0; st < 16; st++) {
            if (st > rg) continue;
            #pragma unroll
            for (int r = 0; r < 4; r++) {
                float pv = exp2f((sacc[st][r] - m4[r]) * 1.4426950408889634f);
                sacc[st][r] = pv;
                l4[r] += pv;
            }
        }
        #pragma unroll
        for (int d = 1; d < 16; d <<= 1)
            #pragma unroll
            for (int r = 0; r < 4; r++)
                l4[r] += __shfl_xor(l4[r], d);

        // O = P V over s-chunks of 32 (chunks c <= rg/2). P via Pb round-trip.
        f32x4 oacc[4];
        #pragma unroll
        for (int ht = 0; ht < 4; ht++) {
            f32x4 z = {0.f, 0.f, 0.f, 0.f};
            oacc[ht] = z;
        }
        #pragma unroll
        for (int c = 0; c < 8; c++) {
            if (c > (rg >> 1)) continue;
            #pragma unroll
            for (int half = 0; half < 2; half++) {
                const int st = c * 2 + half;
                #pragma unroll
                for (int r = 0; r < 4; r++) {
                    short pv = (st <= rg) ? f2bf(sacc[st][r]) : (short)0;
                    pb[(quad * 4 + r) * 40 + half * 16 + cl] = pv;
                }
            }
            __builtin_amdgcn_wave_barrier();
            const bf16x8 pa = *(const bf16x8*)(pb + cl * 40 + quad * 8);
            #pragma unroll
            for (int ht = 0; ht < 4; ht++) {
                const bf16x8 vf = *(const bf16x8*)(Vs + (c * 4 + ht) * 512 + lane * 8);
                oacc[ht] = __builtin_amdgcn_mfma_f32_16x16x32_bf16(pa, vf, oacc[ht], 0, 0, 0);
            }
            __builtin_amdgcn_wave_barrier();
        }

        // Out: O row r is in the same lanes as l4[r].
        #pragma unroll
        for (int r = 0; r < 4; r++) {
            const float inv = 1.0f / l4[r];
            float* op = out + (long)(b * T_ + base + quad * 4 + r) * H_ + cl;
            #pragma unroll
            for (int ht = 0; ht < 4; ht++)
                op[ht * 16] = oacc[ht][r] * inv;
        }
    }
}

// ---------------------------------------------------------------------------
extern "C" void kernel_launch(void* const* d_in, const int* in_sizes, int n_in,
                              void* d_out, int out_size, void* d_ws, size_t ws_size,
                              hipStream_t stream) {
    const float* x  = (const float*)d_in[0];
    const float* Wq = (const float*)d_in[1];
    const float* Wk = (const float*)d_in[2];
    const float* Wv = (const float*)d_in[3];
    float* out = (float*)d_out;

    short* wp = (short*)d_ws;   // packed W: 73728 shorts = 147 KB

    pack_w_kernel<<<288, 256, 0, stream>>>(Wq, Wk, Wv, wp);
    fused_kernel<<<B_, 512, 0, stream>>>(x, wp, out);
}